// Round 4
// baseline (123.473 us; speedup 1.0000x reference)
//
#include <hip/hip_runtime.h>
#include <math.h>

#define BB 65536
#define DD 256
#define KK 10
#define LOG_2PI 1.8378770664093453f

// Coefficient table + per-k constant in MODULE GLOBALS (not d_ws — the
// harness re-poisons the 256 MiB workspace with two ~42 us fills in the
// timed graph unconditionally; and NOT fused — r1/r3 showed per-block
// in-kernel prep makes the whole kernel latency-serialized, 42-80 us).
__device__ float4 g_tab4[1280];   // 20 KB, f4 slots, same layout as round 0
__device__ float  g_C[KK];

// ---------------------------------------------------------------------------
// Prep: identical to round-0/2 prep (bit-identical tab/C), writes module
// globals. grid = K blocks x 256 threads.
// ---------------------------------------------------------------------------
__global__ __launch_bounds__(DD) void gmvae_prep(
    const float* __restrict__ mu_table,
    const float* __restrict__ logvar_table)
{
    float* tab = reinterpret_cast<float*>(g_tab4);
    const int k = blockIdx.x;
    const int d = threadIdx.x;
    const float lv = logvar_table[k * DD + d];
    const float m  = mu_table[k * DD + d];
    const float iv = expf(-lv);          // exact 1.0 when lv==0
    const float a  = m * iv;

    const int f    = d >> 2;             // global f4 index 0..63
    const int s    = f >> 4;             // stage 0..3
    const int c    = (f >> 2) & 3;       // wave chunk 0..3
    const int jj   = f & 3;              // f4 within (s,c)
    const int comp = d & 3;
    const int idx_f4 = ((s * 4 + jj) * KK + k) * 2;   // iv slot
    const int base   = c * 1280 + idx_f4 * 4 + comp;
    tab[base]     = iv;                  // half 0
    tab[base + 4] = -2.0f * a;           // half 1 (next f4)

    float p = fmaf(m, a, lv);            // mu^2*iv + lv
    __shared__ float red[4];
    #pragma unroll
    for (int off = 32; off > 0; off >>= 1)
        p += __shfl_down(p, off, 64);
    if ((threadIdx.x & 63) == 0)
        red[threadIdx.x >> 6] = p;
    __syncthreads();
    if (threadIdx.x == 0) {
        const float s2 = (red[0] + red[1]) + (red[2] + red[3]);
        g_C[k] = -0.5f * (s2 + 256.0f * LOG_2PI) + logf(0.1f);
    }
}

__device__ __forceinline__ float rl(float v, int lane) {
    return __int_as_float(__builtin_amdgcn_readlane(__float_as_int(v), lane));
}

// ---------------------------------------------------------------------------
// Main, R=2 rows/lane, SINGLE-buffered LDS for 4 blocks/CU.
// r0 vs r2 ledger showed main is memory-LATENCY-bound at 2 blocks/CU
// (remainder unchanged when issue count halved). Single buffer [128][17] f4
// = 34.8 KB halves the LDS footprint -> 4 blocks/CU = 16 waves/CU, doubling
// the TLP that covers barrier/vmcnt drains, at the cost of 2 barriers per
// stage transition (7 total). Dim->wave mapping, accumulation order and
// epilogue are bit-identical to round 2.
// grid = B/128 = 512 blocks.
// ---------------------------------------------------------------------------
__global__ __launch_bounds__(256) void gmvae_main(
    const float* __restrict__ q_z,
    float* __restrict__ out)
{
    __shared__ float4 buf[128 * 17];               // 34.8 KB, row stride 17
    float* comb = reinterpret_cast<float*>(buf);   // aliased in epilogue

    const int t    = threadIdx.x;
    const int r    = t & 63;                                   // lane
    const int c    = __builtin_amdgcn_readfirstlane(t >> 6);   // wave id
    const int row0 = blockIdx.x * 128;

    const float4* __restrict__ q4 = reinterpret_cast<const float4*>(q_z);

    // thread's staging slice: 8 f4 per stage (128 rows x 16 f4 / 256 thr)
    const int rr0 = t >> 4;
    const int ff  = t & 15;

    // ---- prologue: issue stage-0 q loads first (HBM latency)
    float4 v[8];
    #pragma unroll
    for (int i = 0; i < 8; ++i)
        v[i] = q4[(size_t)(row0 + i * 16 + rr0) * 64 + 0 * 16 + ff];

    // one-time coefficient slice load (L2-hot, prep just wrote it)
    const float4* __restrict__ t4 = g_tab4 + c * 320;
    float4 w[5];
    #pragma unroll
    for (int i = 0; i < 5; ++i)
        w[i] = t4[i * 64 + r];

    float accA[KK], accB[KK];
    #pragma unroll
    for (int k = 0; k < KK; ++k) { accA[k] = 0.f; accB[k] = 0.f; }

    #pragma unroll
    for (int i = 0; i < 8; ++i)
        buf[(i * 16 + rr0) * 17 + ff] = v[i];
    __syncthreads();

    #pragma unroll
    for (int s = 0; s < 4; ++s) {
        // issue next stage's global loads (hide under compute)
        if (s < 3) {
            #pragma unroll
            for (int i = 0; i < 8; ++i)
                v[i] = q4[(size_t)(row0 + i * 16 + rr0) * 64 + (s + 1) * 16 + ff];
        }

        // compute stage s from buf; coefficients via readlane, each
        // wave-uniform broadcast reused for both rows (r and r+64)
        const float4* bpA = buf + r * 17 + c * 4;
        const float4* bpB = bpA + 64 * 17;
        #pragma unroll
        for (int jj = 0; jj < 4; ++jj) {
            const float4 qa = bpA[jj];
            const float4 qb = bpB[jj];
            const float ax2 = qa.x * qa.x, ay2 = qa.y * qa.y;
            const float az2 = qa.z * qa.z, aw2 = qa.w * qa.w;
            const float bx2 = qb.x * qb.x, by2 = qb.y * qb.y;
            const float bz2 = qb.z * qb.z, bw2 = qb.w * qb.w;
            #pragma unroll
            for (int k = 0; k < KK; ++k) {
                const int flat = ((s * 4 + jj) * KK + k) * 2;  // iv f4 slot
                const int i = flat >> 6;
                const int L = flat & 63;                       // na at L+1
                const float4 wv = w[i];
                const float ivx = rl(wv.x, L), nax = rl(wv.x, L + 1);
                const float ivy = rl(wv.y, L), nay = rl(wv.y, L + 1);
                const float ivz = rl(wv.z, L), naz = rl(wv.z, L + 1);
                const float ivw = rl(wv.w, L), naw = rl(wv.w, L + 1);
                accA[k] = fmaf(ax2, ivx, accA[k]);
                accA[k] = fmaf(qa.x, nax, accA[k]);
                accA[k] = fmaf(ay2, ivy, accA[k]);
                accA[k] = fmaf(qa.y, nay, accA[k]);
                accA[k] = fmaf(az2, ivz, accA[k]);
                accA[k] = fmaf(qa.z, naz, accA[k]);
                accA[k] = fmaf(aw2, ivw, accA[k]);
                accA[k] = fmaf(qa.w, naw, accA[k]);
                accB[k] = fmaf(bx2, ivx, accB[k]);
                accB[k] = fmaf(qb.x, nax, accB[k]);
                accB[k] = fmaf(by2, ivy, accB[k]);
                accB[k] = fmaf(qb.y, nay, accB[k]);
                accB[k] = fmaf(bz2, ivz, accB[k]);
                accB[k] = fmaf(qb.z, naz, accB[k]);
                accB[k] = fmaf(bw2, ivw, accB[k]);
                accB[k] = fmaf(qb.w, naw, accB[k]);
            }
        }

        // single buffer: drain reads, overwrite with stage s+1, publish
        if (s < 3) {
            __syncthreads();           // all waves done reading stage s
            #pragma unroll
            for (int i = 0; i < 8; ++i)
                buf[(i * 16 + rr0) * 17 + ff] = v[i];
            __syncthreads();           // stage s+1 visible
        }
    }

    // cross-wave combine: rows 0-63 from accA at comb[t], rows 64-127 from
    // accB at comb[256+t] (stride 11, odd -> conflict-free; 22.5 KB < buf)
    __syncthreads();                   // all LDS q reads done; safe to alias
    #pragma unroll
    for (int k = 0; k < KK; ++k) {
        comb[t * 11 + k]         = accA[k];
        comb[(256 + t) * 11 + k] = accB[k];
    }
    __syncthreads();

    if (t < 128) {                     // waves 0-1 epilogue: row = row0 + t
        const int hb = t >> 6;         // 0: accA rows, 1: accB rows
        const int rr = t & 63;
        const int cb = hb * 256 + rr;
        float l[KK];
        #pragma unroll
        for (int k = 0; k < KK; ++k) {
            const float vsum =
                ((comb[cb * 11 + k]         + comb[(cb + 64) * 11 + k]) +
                 (comb[(cb + 128) * 11 + k] + comb[(cb + 192) * 11 + k]));
            l[k] = fmaf(vsum, -0.5f, g_C[k]);
        }

        float mx = l[0];
        #pragma unroll
        for (int k = 1; k < KK; ++k) mx = fmaxf(mx, l[k]);

        float e[KK];
        float sum = 0.f;
        #pragma unroll
        for (int k = 0; k < KK; ++k) { e[k] = __expf(l[k] - mx); sum += e[k]; }
        const float inv = 1.0f / sum;

        int idx = 0;
        float best = l[0];
        #pragma unroll
        for (int k = 1; k < KK; ++k)
            if (l[k] > best) { best = l[k]; idx = k; }

        const int row = row0 + t;
        float2* __restrict__ o1 =
            reinterpret_cast<float2*>(out) + (size_t)row * 5;
        float2* __restrict__ o2 =
            reinterpret_cast<float2*>(out + (size_t)BB * KK) + (size_t)row * 5;
        #pragma unroll
        for (int k = 0; k < 5; ++k)
            o1[k] = make_float2(l[2 * k], l[2 * k + 1]);
        #pragma unroll
        for (int k = 0; k < 5; ++k)
            o2[k] = make_float2(e[2 * k] * inv, e[2 * k + 1] * inv);
        out[(size_t)2 * BB * KK + row] = (float)idx;
    }
}

extern "C" void kernel_launch(void* const* d_in, const int* in_sizes, int n_in,
                              void* d_out, int out_size, void* d_ws, size_t ws_size,
                              hipStream_t stream) {
    const float* q_z    = (const float*)d_in[0];
    const float* mu     = (const float*)d_in[1];
    const float* logvar = (const float*)d_in[2];
    (void)d_ws; (void)ws_size;          // workspace deliberately untouched
    gmvae_prep<<<KK, DD, 0, stream>>>(mu, logvar);
    gmvae_main<<<BB / 128, 256, 0, stream>>>(q_z, (float*)d_out);
}

// Round 5
// 101.297 us; speedup vs baseline: 1.2189x; 1.2189x over previous
//
#include <hip/hip_runtime.h>
#include <math.h>

#define BB 65536
#define DD 256
#define KK 10
#define LOG_2PI 1.8378770664093453f

// Coefficient table + per-k constant in MODULE GLOBALS.
//  - not d_ws: harness re-poisons the 256 MiB workspace with two ~42 us
//    fills inside the timed graph UNCONDITIONALLY (r0-r4, invariant).
//  - not fused: per-block in-kernel prep latency-serializes the whole
//    kernel (r1: 42 us, r3: 80 us vs ~13.5 us two-kernel main).
//  - DOUBLE-buffered LDS (69.6 KB) is load-bearing: it pins the allocator
//    at 2 blocks/CU -> 256-VGPR budget -> no spills. Any config whose LDS
//    permits 4 blocks/CU caps VGPRs at 128 and this kernel spills ~64 MB
//    of scratch (r1: WRITE 58 MB, r4: WRITE 64 MB, both 42 us). Do not
//    shrink LDS below 80 KB without cutting live registers first.
__device__ float4 g_tab4[1280];   // 20 KB, f4 slots, same layout as round 0
__device__ float  g_C[KK];

// ---------------------------------------------------------------------------
// Prep: identical to round-0 prep (bit-identical tab/C), writes module
// globals. grid = K blocks x 256 threads.
// ---------------------------------------------------------------------------
__global__ __launch_bounds__(DD) void gmvae_prep(
    const float* __restrict__ mu_table,
    const float* __restrict__ logvar_table)
{
    float* tab = reinterpret_cast<float*>(g_tab4);
    const int k = blockIdx.x;
    const int d = threadIdx.x;
    const float lv = logvar_table[k * DD + d];
    const float m  = mu_table[k * DD + d];
    const float iv = expf(-lv);          // exact 1.0 when lv==0
    const float a  = m * iv;

    const int f    = d >> 2;             // global f4 index 0..63
    const int s    = f >> 4;             // stage 0..3
    const int c    = (f >> 2) & 3;       // wave chunk 0..3
    const int jj   = f & 3;              // f4 within (s,c)
    const int comp = d & 3;
    const int idx_f4 = ((s * 4 + jj) * KK + k) * 2;   // iv slot
    const int base   = c * 1280 + idx_f4 * 4 + comp;
    tab[base]     = iv;                  // half 0
    tab[base + 4] = -2.0f * a;           // half 1 (next f4)

    float p = fmaf(m, a, lv);            // mu^2*iv + lv
    __shared__ float red[4];
    #pragma unroll
    for (int off = 32; off > 0; off >>= 1)
        p += __shfl_down(p, off, 64);
    if ((threadIdx.x & 63) == 0)
        red[threadIdx.x >> 6] = p;
    __syncthreads();
    if (threadIdx.x == 0) {
        const float s2 = (red[0] + red[1]) + (red[2] + red[3]);
        g_C[k] = -0.5f * (s2 + 256.0f * LOG_2PI) + logf(0.1f);
    }
}

__device__ __forceinline__ float rl(float v, int lane) {
    return __int_as_float(__builtin_amdgcn_readlane(__float_as_int(v), lane));
}

// ---------------------------------------------------------------------------
// Main, R=2 rows/lane. Block = 256 threads = 4 waves, 128 rows (lane r owns
// rows r and r+64). Wave c owns dim-chunk c — SAME dim->wave mapping,
// accumulation order, and coefficient slots as round 0, so logits are
// bit-identical; each wave-uniform readlane broadcast feeds 2 rows' FMAs.
// grid = B/128 = 512 blocks; LDS 69.6 KB -> 2 blocks/CU (one pass).
// Measured (r2): total 102.1 us, main not in top-5 (<41 us, est ~13.5 us),
// within ~15% of the ~11 us memory floor for 67 MB of q_z.
// ---------------------------------------------------------------------------
__global__ __launch_bounds__(256) void gmvae_main(
    const float* __restrict__ q_z,
    float* __restrict__ out)
{
    __shared__ float4 buf[2 * 128 * 17];           // 69.6 KB, row stride 17
    float* comb = reinterpret_cast<float*>(buf);   // aliased in epilogue

    const int t    = threadIdx.x;
    const int r    = t & 63;                                   // lane
    const int c    = __builtin_amdgcn_readfirstlane(t >> 6);   // wave id
    const int row0 = blockIdx.x * 128;

    const float4* __restrict__ q4 = reinterpret_cast<const float4*>(q_z);

    // thread's staging slice: 8 f4 per stage (128 rows x 16 f4 / 256 thr)
    const int rr0 = t >> 4;
    const int ff  = t & 15;

    // ---- prologue: issue stage-0 q loads first (HBM latency)
    float4 v[8];
    #pragma unroll
    for (int i = 0; i < 8; ++i)
        v[i] = q4[(size_t)(row0 + i * 16 + rr0) * 64 + 0 * 16 + ff];

    // one-time coefficient slice load (L2-hot, prep just wrote it)
    const float4* __restrict__ t4 = g_tab4 + c * 320;
    float4 w[5];
    #pragma unroll
    for (int i = 0; i < 5; ++i)
        w[i] = t4[i * 64 + r];

    float accA[KK], accB[KK];
    #pragma unroll
    for (int k = 0; k < KK; ++k) { accA[k] = 0.f; accB[k] = 0.f; }

    #pragma unroll
    for (int i = 0; i < 8; ++i)
        buf[(i * 16 + rr0) * 17 + ff] = v[i];
    __syncthreads();

    #pragma unroll
    for (int s = 0; s < 4; ++s) {
        // issue next stage's global loads (hide under compute)
        if (s < 3) {
            #pragma unroll
            for (int i = 0; i < 8; ++i)
                v[i] = q4[(size_t)(row0 + i * 16 + rr0) * 64 + (s + 1) * 16 + ff];
        }

        // compute stage s from LDS buf[s&1]; coefficients via readlane,
        // each broadcast reused for both rows (r and r+64)
        const float4* bpA = buf + (s & 1) * (128 * 17) + r * 17 + c * 4;
        const float4* bpB = bpA + 64 * 17;
        #pragma unroll
        for (int jj = 0; jj < 4; ++jj) {
            const float4 qa = bpA[jj];
            const float4 qb = bpB[jj];
            const float ax2 = qa.x * qa.x, ay2 = qa.y * qa.y;
            const float az2 = qa.z * qa.z, aw2 = qa.w * qa.w;
            const float bx2 = qb.x * qb.x, by2 = qb.y * qb.y;
            const float bz2 = qb.z * qb.z, bw2 = qb.w * qb.w;
            #pragma unroll
            for (int k = 0; k < KK; ++k) {
                const int flat = ((s * 4 + jj) * KK + k) * 2;  // iv f4 slot
                const int i = flat >> 6;
                const int L = flat & 63;                       // na at L+1
                const float4 wv = w[i];
                const float ivx = rl(wv.x, L), nax = rl(wv.x, L + 1);
                const float ivy = rl(wv.y, L), nay = rl(wv.y, L + 1);
                const float ivz = rl(wv.z, L), naz = rl(wv.z, L + 1);
                const float ivw = rl(wv.w, L), naw = rl(wv.w, L + 1);
                accA[k] = fmaf(ax2, ivx, accA[k]);
                accA[k] = fmaf(qa.x, nax, accA[k]);
                accA[k] = fmaf(ay2, ivy, accA[k]);
                accA[k] = fmaf(qa.y, nay, accA[k]);
                accA[k] = fmaf(az2, ivz, accA[k]);
                accA[k] = fmaf(qa.z, naz, accA[k]);
                accA[k] = fmaf(aw2, ivw, accA[k]);
                accA[k] = fmaf(qa.w, naw, accA[k]);
                accB[k] = fmaf(bx2, ivx, accB[k]);
                accB[k] = fmaf(qb.x, nax, accB[k]);
                accB[k] = fmaf(by2, ivy, accB[k]);
                accB[k] = fmaf(qb.y, nay, accB[k]);
                accB[k] = fmaf(bz2, ivz, accB[k]);
                accB[k] = fmaf(qb.z, naz, accB[k]);
                accB[k] = fmaf(bw2, ivw, accB[k]);
                accB[k] = fmaf(qb.w, naw, accB[k]);
            }
        }

        // stage s+1 into the other buffer, one barrier per stage
        if (s < 3) {
            float4* wp = buf + ((s + 1) & 1) * (128 * 17);
            #pragma unroll
            for (int i = 0; i < 8; ++i)
                wp[(i * 16 + rr0) * 17 + ff] = v[i];
            __syncthreads();
        }
    }

    // cross-wave combine: rows 0-63 from accA at comb[t], rows 64-127 from
    // accB at comb[256+t] (stride 11, odd -> conflict-free)
    __syncthreads();                   // all LDS q reads done; safe to alias
    #pragma unroll
    for (int k = 0; k < KK; ++k) {
        comb[t * 11 + k]         = accA[k];
        comb[(256 + t) * 11 + k] = accB[k];
    }
    __syncthreads();

    if (t < 128) {                     // waves 0-1 epilogue: row = row0 + t
        const int hb = t >> 6;         // 0: accA rows, 1: accB rows
        const int rr = t & 63;
        const int cb = hb * 256 + rr;
        float l[KK];
        #pragma unroll
        for (int k = 0; k < KK; ++k) {
            const float vsum =
                ((comb[cb * 11 + k]         + comb[(cb + 64) * 11 + k]) +
                 (comb[(cb + 128) * 11 + k] + comb[(cb + 192) * 11 + k]));
            l[k] = fmaf(vsum, -0.5f, g_C[k]);
        }

        float mx = l[0];
        #pragma unroll
        for (int k = 1; k < KK; ++k) mx = fmaxf(mx, l[k]);

        float e[KK];
        float sum = 0.f;
        #pragma unroll
        for (int k = 0; k < KK; ++k) { e[k] = __expf(l[k] - mx); sum += e[k]; }
        const float inv = 1.0f / sum;

        int idx = 0;
        float best = l[0];
        #pragma unroll
        for (int k = 1; k < KK; ++k)
            if (l[k] > best) { best = l[k]; idx = k; }

        const int row = row0 + t;
        float2* __restrict__ o1 =
            reinterpret_cast<float2*>(out) + (size_t)row * 5;
        float2* __restrict__ o2 =
            reinterpret_cast<float2*>(out + (size_t)BB * KK) + (size_t)row * 5;
        #pragma unroll
        for (int k = 0; k < 5; ++k)
            o1[k] = make_float2(l[2 * k], l[2 * k + 1]);
        #pragma unroll
        for (int k = 0; k < 5; ++k)
            o2[k] = make_float2(e[2 * k] * inv, e[2 * k + 1] * inv);
        out[(size_t)2 * BB * KK + row] = (float)idx;
    }
}

extern "C" void kernel_launch(void* const* d_in, const int* in_sizes, int n_in,
                              void* d_out, int out_size, void* d_ws, size_t ws_size,
                              hipStream_t stream) {
    const float* q_z    = (const float*)d_in[0];
    const float* mu     = (const float*)d_in[1];
    const float* logvar = (const float*)d_in[2];
    (void)d_ws; (void)ws_size;          // workspace deliberately untouched
    gmvae_prep<<<KK, DD, 0, stream>>>(mu, logvar);
    gmvae_main<<<BB / 128, 256, 0, stream>>>(q_z, (float*)d_out);
}